// Round 1
// baseline (944.730 us; speedup 1.0000x reference)
//
#include <hip/hip_runtime.h>
#include <stdint.h>

#define NTOK   4096
#define DM     2048
#define DMLP   8192
#define NEXP   8
#define NRANK  16
#define SCAL   2.0f

typedef __bf16 bf16x8 __attribute__((ext_vector_type(8)));
typedef float  f32x4  __attribute__((ext_vector_type(4)));
typedef unsigned short u16;

__device__ __forceinline__ u16 f2bf(float f) {
  unsigned u = __float_as_uint(f);
  u += 0x7fffu + ((u >> 16) & 1u);   // RNE
  return (u16)(u >> 16);
}
__device__ __forceinline__ float bf2f(unsigned s) {
  return __uint_as_float(s << 16);
}

__device__ __forceinline__ void gload_lds16(const void* g, void* l) {
  __builtin_amdgcn_global_load_lds((const __attribute__((address_space(1))) void*)g,
                                   (__attribute__((address_space(3))) void*)l, 16, 0, 0);
}

__device__ __forceinline__ void unpack16(const u16* p, float* o) {
  uint4 a = ((const uint4*)p)[0];
  uint4 b = ((const uint4*)p)[1];
  o[0]=bf2f(a.x&0xffffu);  o[1]=bf2f(a.x>>16);
  o[2]=bf2f(a.y&0xffffu);  o[3]=bf2f(a.y>>16);
  o[4]=bf2f(a.z&0xffffu);  o[5]=bf2f(a.z>>16);
  o[6]=bf2f(a.w&0xffffu);  o[7]=bf2f(a.w>>16);
  o[8]=bf2f(b.x&0xffffu);  o[9]=bf2f(b.x>>16);
  o[10]=bf2f(b.y&0xffffu); o[11]=bf2f(b.y>>16);
  o[12]=bf2f(b.z&0xffffu); o[13]=bf2f(b.z>>16);
  o[14]=bf2f(b.w&0xffffu); o[15]=bf2f(b.w>>16);
}

// ---------------- generic f32 -> bf16 convert (n4 = elem_count/4) ----------------
__global__ void cvt_kernel(const float* __restrict__ src, u16* __restrict__ dst, int n4) {
  int i = blockIdx.x * blockDim.x + threadIdx.x;
  int stride = gridDim.x * blockDim.x;
  for (; i < n4; i += stride) {
    float4 v = ((const float4*)src)[i];
    ushort4 o;
    o.x = f2bf(v.x); o.y = f2bf(v.y); o.z = f2bf(v.z); o.w = f2bf(v.w);
    ((ushort4*)dst)[i] = o;
  }
}

// ---------------- router: logits/softmax/argmax + x->bf16 ----------------
__global__ void router_kernel(const float* __restrict__ x,
                              const float* __restrict__ rw,
                              const float* __restrict__ rb,
                              u16* __restrict__ xb,
                              int* __restrict__ idx,
                              float* __restrict__ out_rout,
                              float* __restrict__ out_ec) {
  const int wave = threadIdx.x >> 6;
  const int lane = threadIdx.x & 63;
  const int m = blockIdx.x * 4 + wave;

  const float4* xrow = (const float4*)(x + (size_t)m * DM + lane * 32);
  float4 xv[8];
#pragma unroll
  for (int i = 0; i < 8; ++i) xv[i] = xrow[i];

  // convert + store bf16 x (64B per lane, coalesced)
  uint4 o[4];
  unsigned* op = (unsigned*)o;
#pragma unroll
  for (int i = 0; i < 8; ++i) {
    op[2*i]   = (unsigned)f2bf(xv[i].x) | ((unsigned)f2bf(xv[i].y) << 16);
    op[2*i+1] = (unsigned)f2bf(xv[i].z) | ((unsigned)f2bf(xv[i].w) << 16);
  }
  uint4* xdst = (uint4*)(xb + (size_t)m * DM + lane * 32);
#pragma unroll
  for (int i = 0; i < 4; ++i) xdst[i] = o[i];

  float lg[NEXP];
#pragma unroll
  for (int e = 0; e < NEXP; ++e) {
    const float4* wrow = (const float4*)(rw + (size_t)e * DM + lane * 32);
    float s = 0.f;
#pragma unroll
    for (int i = 0; i < 8; ++i) {
      float4 wv = wrow[i];
      s += xv[i].x*wv.x + xv[i].y*wv.y + xv[i].z*wv.z + xv[i].w*wv.w;
    }
#pragma unroll
    for (int off = 32; off > 0; off >>= 1) s += __shfl_xor(s, off, 64);
    lg[e] = s + rb[e];
  }

  float mx = lg[0];
#pragma unroll
  for (int e = 1; e < NEXP; ++e) mx = fmaxf(mx, lg[e]);
  float ex[NEXP], se = 0.f;
#pragma unroll
  for (int e = 0; e < NEXP; ++e) { ex[e] = expf(lg[e] - mx); se += ex[e]; }
  float inv = 1.f / se;
  int best = 0; float bv = lg[0];
#pragma unroll
  for (int e = 1; e < NEXP; ++e) if (lg[e] > bv) { bv = lg[e]; best = e; }

  if (lane == 0) {
    idx[m] = best;
#pragma unroll
    for (int e = 0; e < NEXP; ++e) {
      float r = ex[e] * inv;
      out_rout[(size_t)m * NEXP + e] = r;
      float hard = (e == best) ? 1.f : 0.f;
      out_ec[(size_t)m * NEXP + e] = (hard - r) + r;  // match jax expr
    }
  }
}

// ---------------- GEMM core (128x128 tile, BK=32, dbuf global_load_lds) ----------------
// MODE 0: t_all = xb @ Aab^T           (K=2048, N=256)  -> bf16
// MODE 1: gate/up fused + lora + silu  (K=2048, blockN=64 real cols) -> hb bf16
// MODE 2: down + lora                  (K=8192, N=2048) -> f32 out
// MODE 3: t_down split-K partials      (K=1024/split, N=128) -> f32 partials
template<int MODE>
__global__ __launch_bounds__(256, 2)
void gemm_kernel(const u16* __restrict__ A,
                 const u16* __restrict__ B0,
                 const u16* __restrict__ B1,
                 const u16* __restrict__ tA,
                 const int* __restrict__ idx,
                 const float* __restrict__ BL0,
                 const float* __restrict__ BL1,
                 void* __restrict__ Cout)
{
  constexpr int KT  = (MODE <= 1) ? 2048 : 8192;   // A row stride (=K total)
  constexpr int LDB = (MODE <= 1) ? 2048 : 8192;   // B row stride
  constexpr int NKI = (MODE == 3) ? 32 : KT / 32;

  __shared__ u16 lds[16384];  // 32 KB: [buf2][A|B][128 rows][32 cols] bf16

  const int tid = threadIdx.x;
  const int w = tid >> 6;
  const int l = tid & 63;
  const int wm = w >> 1, wn = w & 1;
  const int mtile = blockIdx.x;
  const int ntile = (MODE == 3) ? 0 : (int)blockIdx.y;
  const int ks    = (MODE == 3) ? (int)blockIdx.y : 0;
  const int kb0   = ks * 1024;

  // staging map: load i in {0,1}: LDS byte (per half) = i*4096 + w*1024 + lane*16
  int srow[2];
  srow[0] = w * 16 + (l >> 2);
  srow[1] = 64 + srow[0];
  const int scol = (l & 3) * 8;

  const u16* aptr[2];
  const u16* bptr[2];
#pragma unroll
  for (int i = 0; i < 2; ++i) {
    aptr[i] = A + (size_t)(mtile * 128 + srow[i]) * KT + kb0 + scol;
    int j = srow[i];
    if (MODE == 1) {
      // B-tile row j: 16-col blocks alternate gate/up of the same real columns
      int c = ntile * 64 + ((j >> 5) << 4) + (j & 15);
      const u16* src = ((j >> 4) & 1) ? B1 : B0;
      bptr[i] = src + (size_t)c * LDB + kb0 + scol;
    } else {
      bptr[i] = B0 + (size_t)(ntile * 128 + j) * LDB + kb0 + scol;
    }
  }

  char* ldsc = (char*)lds;
  auto stage = [&](int buf, int kt) {
    const int kk = kt * 32;
    char* base = ldsc + buf * 16384;
#pragma unroll
    for (int i = 0; i < 2; ++i) {
      gload_lds16(aptr[i] + kk, base + i * 4096 + w * 1024);
      gload_lds16(bptr[i] + kk, base + 8192 + i * 4096 + w * 1024);
    }
  };

  f32x4 acc[4][4];
  f32x4 zf = {0.f, 0.f, 0.f, 0.f};
#pragma unroll
  for (int a = 0; a < 4; ++a)
#pragma unroll
    for (int b = 0; b < 4; ++b) acc[a][b] = zf;

  stage(0, 0);
  __syncthreads();

  const int kc   = (l >> 4) * 16;        // byte offset of 8-elem k-chunk
  const int arow = wm * 64 + (l & 15);
  const int brow = wn * 64 + (l & 15);

  for (int kt = 0; kt < NKI; ++kt) {
    const int buf = kt & 1;
    if (kt + 1 < NKI) stage(buf ^ 1, kt + 1);
    const char* bA = ldsc + buf * 16384;
    const char* bB = bA + 8192;
    bf16x8 af[4], bfr[4];
#pragma unroll
    for (int fm = 0; fm < 4; ++fm)
      af[fm] = *(const bf16x8*)(bA + (arow + fm * 16) * 64 + kc);
#pragma unroll
    for (int fn = 0; fn < 4; ++fn)
      bfr[fn] = *(const bf16x8*)(bB + (brow + fn * 16) * 64 + kc);
#pragma unroll
    for (int fm = 0; fm < 4; ++fm)
#pragma unroll
      for (int fn = 0; fn < 4; ++fn)
        acc[fm][fn] = __builtin_amdgcn_mfma_f32_16x16x32_bf16(af[fm], bfr[fn], acc[fm][fn], 0, 0, 0);
    __syncthreads();
  }

  const int lq = l >> 4;   // C/D: row = lq*4 + reg, col = l&15 (m89-verified)
  const int lr = l & 15;

  if (MODE == 0) {
    u16* C = (u16*)Cout;
#pragma unroll
    for (int fm = 0; fm < 4; ++fm)
#pragma unroll
      for (int fn = 0; fn < 4; ++fn)
        for (int j = 0; j < 4; ++j) {
          int m = mtile * 128 + wm * 64 + fm * 16 + lq * 4 + j;
          int c = ntile * 128 + wn * 64 + fn * 16 + lr;
          C[(size_t)m * 256 + c] = f2bf(acc[fm][fn][j]);
        }
  } else if (MODE == 1) {
    u16* hb = (u16*)Cout;
#pragma unroll
    for (int fm = 0; fm < 4; ++fm) {
      for (int j = 0; j < 4; ++j) {
        const int m = mtile * 128 + wm * 64 + fm * 16 + lq * 4 + j;
        const int e = idx[m];
        float tg[16], tu[16];
        unpack16(tA + (size_t)m * 256 + e * NRANK, tg);
        unpack16(tA + (size_t)m * 256 + 128 + e * NRANK, tu);
#pragma unroll
        for (int p = 0; p < 2; ++p) {
          const int c = ntile * 64 + (wn * 2 + p) * 16 + lr;
          const float* bg = BL0 + (size_t)(e * DMLP + c) * NRANK;
          const float* bu = BL1 + (size_t)(e * DMLP + c) * NRANK;
          float g = acc[fm][2 * p][j];
          float u = acc[fm][2 * p + 1][j];
          float sg = 0.f, su = 0.f;
#pragma unroll
          for (int r = 0; r < NRANK; ++r) { sg += tg[r] * bg[r]; su += tu[r] * bu[r]; }
          g += SCAL * sg;
          u += SCAL * su;
          float h = g / (1.f + __expf(-g)) * u;   // silu(g)*u
          hb[(size_t)m * DMLP + c] = f2bf(h);
        }
      }
    }
  } else if (MODE == 2) {
    float* C = (float*)Cout;
#pragma unroll
    for (int fm = 0; fm < 4; ++fm) {
      for (int j = 0; j < 4; ++j) {
        const int m = mtile * 128 + wm * 64 + fm * 16 + lq * 4 + j;
        const int e = idx[m];
        float tv[16];
        unpack16(tA + (size_t)m * 128 + e * NRANK, tv);
#pragma unroll
        for (int fn = 0; fn < 4; ++fn) {
          const int c = ntile * 128 + wn * 64 + fn * 16 + lr;
          const float* bd = BL0 + (size_t)(e * DM + c) * NRANK;
          float s = 0.f;
#pragma unroll
          for (int r = 0; r < NRANK; ++r) s += tv[r] * bd[r];
          C[(size_t)m * DM + c] = acc[fm][fn][j] + SCAL * s;
        }
      }
    }
  } else {
    float* P = (float*)Cout + (size_t)ks * NTOK * 128;
#pragma unroll
    for (int fm = 0; fm < 4; ++fm)
#pragma unroll
      for (int fn = 0; fn < 4; ++fn)
        for (int j = 0; j < 4; ++j) {
          int m = mtile * 128 + wm * 64 + fm * 16 + lq * 4 + j;
          int c = wn * 64 + fn * 16 + lr;
          P[(size_t)m * 128 + c] = acc[fm][fn][j];
        }
  }
}

// ---------------- t_down split-K reduce (deterministic) ----------------
__global__ void td_reduce(const float* __restrict__ part, u16* __restrict__ td) {
  int i = blockIdx.x * blockDim.x + threadIdx.x;  // 0 .. 4096*128-1
  float s = 0.f;
#pragma unroll
  for (int k = 0; k < 8; ++k) s += part[(size_t)k * NTOK * 128 + i];
  td[i] = f2bf(s);
}

extern "C" void kernel_launch(void* const* d_in, const int* in_sizes, int n_in,
                              void* d_out, int out_size, void* d_ws, size_t ws_size,
                              hipStream_t stream) {
  const float* x  = (const float*)d_in[0];
  const float* wg = (const float*)d_in[1];
  const float* wu = (const float*)d_in[2];
  const float* wd = (const float*)d_in[3];
  const float* rw = (const float*)d_in[4];
  const float* rb = (const float*)d_in[5];
  const float* Ag = (const float*)d_in[6];
  const float* Bg = (const float*)d_in[7];
  const float* Au = (const float*)d_in[8];
  const float* Bu = (const float*)d_in[9];
  const float* Ad = (const float*)d_in[10];
  const float* Bd = (const float*)d_in[11];

  float* out      = (float*)d_out;
  float* out_rout = out + (size_t)NTOK * DM;
  float* out_ec   = out_rout + (size_t)NTOK * NEXP;

  char* ws = (char*)d_ws;
  size_t off = 0;
  auto take = [&](size_t b) { void* p = ws + off; off += (b + 255) & ~(size_t)255; return p; };
  u16*   xb   = (u16*)take((size_t)NTOK * DM * 2);
  u16*   wgb  = (u16*)take((size_t)DMLP * DM * 2);
  u16*   wub  = (u16*)take((size_t)DMLP * DM * 2);
  u16*   wdb  = (u16*)take((size_t)DM * DMLP * 2);
  u16*   Aab  = (u16*)take((size_t)256 * DM * 2);       // [A_gate;A_up] flattened
  u16*   Adb  = (u16*)take((size_t)128 * DMLP * 2);     // A_down flattened
  u16*   tall = (u16*)take((size_t)NTOK * 256 * 2);
  u16*   hb   = (u16*)take((size_t)NTOK * DMLP * 2);
  float* tdp  = (float*)take((size_t)8 * NTOK * 128 * 4);
  u16*   td   = (u16*)take((size_t)NTOK * 128 * 2);
  int*   idx  = (int*)take((size_t)NTOK * 4);
  if (off > ws_size) return;  // workspace too small: bail (bench will flag)

  cvt_kernel<<<1024, 256, 0, stream>>>(wg, wgb, DMLP * DM / 4);
  cvt_kernel<<<1024, 256, 0, stream>>>(wu, wub, DMLP * DM / 4);
  cvt_kernel<<<1024, 256, 0, stream>>>(wd, wdb, DM * DMLP / 4);
  cvt_kernel<<<64, 256, 0, stream>>>(Ag, Aab, 128 * DM / 4);
  cvt_kernel<<<64, 256, 0, stream>>>(Au, Aab + 128 * DM, 128 * DM / 4);
  cvt_kernel<<<128, 256, 0, stream>>>(Ad, Adb, 128 * DMLP / 4);

  router_kernel<<<NTOK / 4, 256, 0, stream>>>(x, rw, rb, xb, idx, out_rout, out_ec);

  // t_all = xb @ [A_gate;A_up]^T  -> [4096, 256] bf16
  gemm_kernel<0><<<dim3(32, 2), 256, 0, stream>>>(xb, Aab, nullptr, nullptr, nullptr,
                                                  nullptr, nullptr, tall);
  // gate/up fused + lora + silu*mul -> hb [4096, 8192] bf16
  gemm_kernel<1><<<dim3(32, 128), 256, 0, stream>>>(xb, wgb, wub, tall, idx,
                                                    Bg, Bu, hb);
  // t_down partials: hb @ A_down^T, 8-way K-split
  gemm_kernel<3><<<dim3(32, 8), 256, 0, stream>>>(hb, Adb, nullptr, nullptr, nullptr,
                                                  nullptr, nullptr, tdp);
  td_reduce<<<NTOK * 128 / 256, 256, 0, stream>>>(tdp, td);
  // down proj + lora -> out f32
  gemm_kernel<2><<<dim3(32, 16), 256, 0, stream>>>(hb, wdb, nullptr, td, idx,
                                                   Bd, nullptr, out);
}

// Round 2
// 700.848 us; speedup vs baseline: 1.3480x; 1.3480x over previous
//
#include <hip/hip_runtime.h>
#include <stdint.h>

#define NTOK   4096
#define DM     2048
#define DMLP   8192
#define NEXP   8
#define NRANK  16
#define SCAL   2.0f

// Wide-A strides (LoRA folded into K):
//   xa: [4096, 2304]  = [x_bf16 | SCAL*t_gate_masked(128) | SCAL*t_up_masked(128)]
//   ha: [4096, 8320]  = [h_bf16 | SCAL*t_down_masked(128)]
#define LDXA 2304
#define LDHA 8320

typedef __bf16 bf16x8 __attribute__((ext_vector_type(8)));
typedef float  f32x4  __attribute__((ext_vector_type(4)));
typedef unsigned short u16;

__device__ __forceinline__ u16 f2bf(float f) {
  unsigned u = __float_as_uint(f);
  u += 0x7fffu + ((u >> 16) & 1u);   // RNE
  return (u16)(u >> 16);
}

__device__ __forceinline__ void gload_lds16(const void* g, void* l) {
  __builtin_amdgcn_global_load_lds((const __attribute__((address_space(1))) void*)g,
                                   (__attribute__((address_space(3))) void*)l, 16, 0, 0);
}

// ---------------- generic f32 -> bf16 convert ----------------
__global__ void cvt_kernel(const float* __restrict__ src, u16* __restrict__ dst, int n4) {
  int i = blockIdx.x * blockDim.x + threadIdx.x;
  int stride = gridDim.x * blockDim.x;
  for (; i < n4; i += stride) {
    float4 v = ((const float4*)src)[i];
    ushort4 o;
    o.x = f2bf(v.x); o.y = f2bf(v.y); o.z = f2bf(v.z); o.w = f2bf(v.w);
    ((ushort4*)dst)[i] = o;
  }
}

// ---------------- build extended weight matrices ----------------
// dst row o = [bf16(W[o,:din]) | ext], ext[c] = Bm[e][o][r] at c-extoff=e*16+r, else 0
__global__ void build_wx(const float* __restrict__ W,
                         const float* __restrict__ Bm,
                         u16* __restrict__ dst,
                         int din, int ldx, int extoff, int browstride) {
  const int o = blockIdx.x;
  const int tid = threadIdx.x;
  u16* drow = dst + (size_t)o * ldx;
  const float* wrow = W + (size_t)o * din;
  for (int c4 = tid; c4 < din / 4; c4 += 256) {
    float4 v = ((const float4*)wrow)[c4];
    ushort4 ov;
    ov.x = f2bf(v.x); ov.y = f2bf(v.y); ov.z = f2bf(v.z); ov.w = f2bf(v.w);
    ((ushort4*)drow)[c4] = ov;
  }
  const int next = ldx - din;
  if (tid < next) {
    int c = tid;
    u16 val = 0;
    if (c >= extoff && c < extoff + NEXP * NRANK) {
      int ce = c - extoff;
      int e = ce >> 4, r = ce & 15;
      val = f2bf(Bm[((size_t)e * browstride + o) * NRANK + r]);
    }
    drow[din + c] = val;
  }
}

// ---------------- router: logits/softmax/argmax + x->bf16 into xa ----------------
__global__ void router_kernel(const float* __restrict__ x,
                              const float* __restrict__ rw,
                              const float* __restrict__ rb,
                              u16* __restrict__ xa,
                              int* __restrict__ idx,
                              float* __restrict__ out_rout,
                              float* __restrict__ out_ec) {
  const int wave = threadIdx.x >> 6;
  const int lane = threadIdx.x & 63;
  const int m = blockIdx.x * 4 + wave;

  const float4* xrow = (const float4*)(x + (size_t)m * DM + lane * 32);
  float4 xv[8];
#pragma unroll
  for (int i = 0; i < 8; ++i) xv[i] = xrow[i];

  uint4 o[4];
  unsigned* op = (unsigned*)o;
#pragma unroll
  for (int i = 0; i < 8; ++i) {
    op[2*i]   = (unsigned)f2bf(xv[i].x) | ((unsigned)f2bf(xv[i].y) << 16);
    op[2*i+1] = (unsigned)f2bf(xv[i].z) | ((unsigned)f2bf(xv[i].w) << 16);
  }
  uint4* xdst = (uint4*)(xa + (size_t)m * LDXA + lane * 32);
#pragma unroll
  for (int i = 0; i < 4; ++i) xdst[i] = o[i];

  float lg[NEXP];
#pragma unroll
  for (int e = 0; e < NEXP; ++e) {
    const float4* wrow = (const float4*)(rw + (size_t)e * DM + lane * 32);
    float s = 0.f;
#pragma unroll
    for (int i = 0; i < 8; ++i) {
      float4 wv = wrow[i];
      s += xv[i].x*wv.x + xv[i].y*wv.y + xv[i].z*wv.z + xv[i].w*wv.w;
    }
#pragma unroll
    for (int off = 32; off > 0; off >>= 1) s += __shfl_xor(s, off, 64);
    lg[e] = s + rb[e];
  }

  float mx = lg[0];
#pragma unroll
  for (int e = 1; e < NEXP; ++e) mx = fmaxf(mx, lg[e]);
  float ex[NEXP], se = 0.f;
#pragma unroll
  for (int e = 0; e < NEXP; ++e) { ex[e] = expf(lg[e] - mx); se += ex[e]; }
  float inv = 1.f / se;
  int best = 0; float bv = lg[0];
#pragma unroll
  for (int e = 1; e < NEXP; ++e) if (lg[e] > bv) { bv = lg[e]; best = e; }

  if (lane == 0) {
    idx[m] = best;
#pragma unroll
    for (int e = 0; e < NEXP; ++e) {
      float r = ex[e] * inv;
      out_rout[(size_t)m * NEXP + e] = r;
      float hard = (e == best) ? 1.f : 0.f;
      out_ec[(size_t)m * NEXP + e] = (hard - r) + r;
    }
  }
}

// ---------------- GEMM core (128x128 tile, BK=32, dbuf global_load_lds, LDS swizzle) ----
// MODE 0: t = xa @ [A_gate;A_up]^T (K=2048) -> masked SCAL*t into xa ext cols
// MODE 1: gate/up fused (K=2304, lora in K) + silu*mul -> ha base cols bf16
// MODE 2: down (K=8320, lora in K) -> f32 out
// MODE 3: t_down split-K partials (hb @ A_down^T) -> f32 partials
template<int MODE>
__global__ __launch_bounds__(256, 2)
void gemm_kernel(const u16* __restrict__ A,
                 const u16* __restrict__ B0,
                 const u16* __restrict__ B1,
                 const int* __restrict__ idx,
                 void* __restrict__ Cout)
{
  constexpr int LDA = (MODE <= 1) ? LDXA : LDHA;
  constexpr int LDB = (MODE == 0) ? 2048 : (MODE == 1) ? LDXA : (MODE == 2) ? LDHA : 8192;
  constexpr int NKI = (MODE == 0) ? 64 : (MODE == 1) ? 72 : (MODE == 2) ? 260 : 32;

  __shared__ u16 lds[16384];  // 32 KB: [buf2][A|B][128 rows][32 cols] bf16 (chunk-swizzled)

  const int tid = threadIdx.x;
  const int w = tid >> 6;
  const int l = tid & 63;
  const int wm = w >> 1, wn = w & 1;
  const int mtile = blockIdx.x;
  const int ntile = (MODE == 3) ? 0 : (int)blockIdx.y;
  const int ks    = (MODE == 3) ? (int)blockIdx.y : 0;
  const int kb0   = (MODE == 3) ? ks * 1024 : 0;

  // staging map: lane l of wave w writes LDS linear bytes (half base) + w*1024 + l*16,
  // i.e. position (row = w*16 + l>>2 (+64), poschunk = l&3).
  // Swizzle: position (r, p) holds global chunk p ^ ((r>>1)&3)  [2-way banks on read]
  int srow[2];
  srow[0] = w * 16 + (l >> 2);
  srow[1] = 64 + srow[0];
  const int chunk = (l & 3) ^ ((srow[0] >> 1) & 3);  // same xor for srow[1] (+64)
  const int scol = chunk * 8;

  const u16* aptr[2];
  const u16* bptr[2];
#pragma unroll
  for (int i = 0; i < 2; ++i) {
    aptr[i] = A + (size_t)(mtile * 128 + srow[i]) * LDA + kb0 + scol;
    int j = srow[i];
    if (MODE == 1) {
      // interleave gate/up at 16-col granularity: same real col -> same lane
      int c = ntile * 64 + ((j >> 5) << 4) + (j & 15);
      const u16* src = ((j >> 4) & 1) ? B1 : B0;
      bptr[i] = src + (size_t)c * LDB + scol;
    } else {
      bptr[i] = B0 + (size_t)(ntile * 128 + j) * LDB + kb0 + scol;
    }
  }

  char* ldsc = (char*)lds;
  auto stage = [&](int buf, int kt) {
    const int kk = kt * 32;
    char* base = ldsc + buf * 16384;
#pragma unroll
    for (int i = 0; i < 2; ++i) {
      gload_lds16(aptr[i] + kk, base + i * 4096 + w * 1024);
      gload_lds16(bptr[i] + kk, base + 8192 + i * 4096 + w * 1024);
    }
  };

  f32x4 acc[4][4];
  f32x4 zf = {0.f, 0.f, 0.f, 0.f};
#pragma unroll
  for (int a = 0; a < 4; ++a)
#pragma unroll
    for (int b = 0; b < 4; ++b) acc[a][b] = zf;

  stage(0, 0);
  __syncthreads();

  const int kq   = l >> 4;               // k-chunk index 0..3
  const int arow = wm * 64 + (l & 15);
  const int brow = wn * 64 + (l & 15);
  const int axor = (kq ^ ((arow >> 1) & 3)) << 4;   // fm*16 doesn't change (row>>1)&3
  const int bxor = (kq ^ ((brow >> 1) & 3)) << 4;

  for (int kt = 0; kt < NKI; ++kt) {
    const int buf = kt & 1;
    if (kt + 1 < NKI) stage(buf ^ 1, kt + 1);
    const char* bA = ldsc + buf * 16384;
    const char* bB = bA + 8192;
    bf16x8 af[4], bfr[4];
#pragma unroll
    for (int fm = 0; fm < 4; ++fm)
      af[fm] = *(const bf16x8*)(bA + (arow + fm * 16) * 64 + axor);
#pragma unroll
    for (int fn = 0; fn < 4; ++fn)
      bfr[fn] = *(const bf16x8*)(bB + (brow + fn * 16) * 64 + bxor);
#pragma unroll
    for (int fm = 0; fm < 4; ++fm)
#pragma unroll
      for (int fn = 0; fn < 4; ++fn)
        acc[fm][fn] = __builtin_amdgcn_mfma_f32_16x16x32_bf16(af[fm], bfr[fn], acc[fm][fn], 0, 0, 0);
    __syncthreads();
  }

  const int lq = l >> 4;   // C/D: row = lq*4 + reg, col = l&15 (m89-verified)
  const int lr = l & 15;

  if (MODE == 0) {
    // masked SCAL*t -> xa ext cols [2048, 2304)
    u16* X = (u16*)Cout;
#pragma unroll
    for (int fm = 0; fm < 4; ++fm)
#pragma unroll
      for (int fn = 0; fn < 4; ++fn)
        for (int j = 0; j < 4; ++j) {
          int m = mtile * 128 + wm * 64 + fm * 16 + lq * 4 + j;
          int c = ntile * 128 + wn * 64 + fn * 16 + lr;     // 0..255
          int e = idx[m];
          u16 v = (((c & 127) >> 4) == e) ? f2bf(SCAL * acc[fm][fn][j]) : (u16)0;
          X[(size_t)m * LDXA + 2048 + c] = v;
        }
  } else if (MODE == 1) {
    u16* H = (u16*)Cout;  // ha
#pragma unroll
    for (int fm = 0; fm < 4; ++fm)
      for (int j = 0; j < 4; ++j) {
        const int m = mtile * 128 + wm * 64 + fm * 16 + lq * 4 + j;
#pragma unroll
        for (int p = 0; p < 2; ++p) {
          const int c = ntile * 64 + (wn * 2 + p) * 16 + lr;
          float g = acc[fm][2 * p][j];
          float u = acc[fm][2 * p + 1][j];
          float h = g / (1.f + __expf(-g)) * u;
          H[(size_t)m * LDHA + c] = f2bf(h);
        }
      }
  } else if (MODE == 2) {
    float* C = (float*)Cout;
#pragma unroll
    for (int fm = 0; fm < 4; ++fm)
#pragma unroll
      for (int fn = 0; fn < 4; ++fn)
        for (int j = 0; j < 4; ++j) {
          int m = mtile * 128 + wm * 64 + fm * 16 + lq * 4 + j;
          int c = ntile * 128 + wn * 64 + fn * 16 + lr;
          C[(size_t)m * DM + c] = acc[fm][fn][j];
        }
  } else {
    float* P = (float*)Cout + (size_t)ks * NTOK * 128;
#pragma unroll
    for (int fm = 0; fm < 4; ++fm)
#pragma unroll
      for (int fn = 0; fn < 4; ++fn)
        for (int j = 0; j < 4; ++j) {
          int m = mtile * 128 + wm * 64 + fm * 16 + lq * 4 + j;
          int c = wn * 64 + fn * 16 + lr;
          P[(size_t)m * 128 + c] = acc[fm][fn][j];
        }
  }
}

// ---------------- t_down split-K reduce -> masked SCAL*td into ha ext cols ----------------
__global__ void td_reduce(const float* __restrict__ part,
                          const int* __restrict__ idx,
                          u16* __restrict__ ha) {
  int i = blockIdx.x * blockDim.x + threadIdx.x;  // 0 .. 4096*128-1
  int m = i >> 7, c = i & 127;
  float s = 0.f;
#pragma unroll
  for (int k = 0; k < 8; ++k) s += part[(size_t)k * NTOK * 128 + i];
  u16 v = ((c >> 4) == idx[m]) ? f2bf(SCAL * s) : (u16)0;
  ha[(size_t)m * LDHA + 8192 + c] = v;
}

extern "C" void kernel_launch(void* const* d_in, const int* in_sizes, int n_in,
                              void* d_out, int out_size, void* d_ws, size_t ws_size,
                              hipStream_t stream) {
  const float* x  = (const float*)d_in[0];
  const float* wg = (const float*)d_in[1];
  const float* wu = (const float*)d_in[2];
  const float* wd = (const float*)d_in[3];
  const float* rw = (const float*)d_in[4];
  const float* rb = (const float*)d_in[5];
  const float* Ag = (const float*)d_in[6];
  const float* Bg = (const float*)d_in[7];
  const float* Au = (const float*)d_in[8];
  const float* Bu = (const float*)d_in[9];
  const float* Ad = (const float*)d_in[10];
  const float* Bd = (const float*)d_in[11];

  float* out      = (float*)d_out;
  float* out_rout = out + (size_t)NTOK * DM;
  float* out_ec   = out_rout + (size_t)NTOK * NEXP;

  char* ws = (char*)d_ws;
  size_t off = 0;
  auto take = [&](size_t b) { void* p = ws + off; off += (b + 255) & ~(size_t)255; return p; };
  u16*   xa   = (u16*)take((size_t)NTOK * LDXA * 2);
  u16*   ha   = (u16*)take((size_t)NTOK * LDHA * 2);
  u16*   wgx  = (u16*)take((size_t)DMLP * LDXA * 2);
  u16*   wux  = (u16*)take((size_t)DMLP * LDXA * 2);
  u16*   wdx  = (u16*)take((size_t)DM * LDHA * 2);
  u16*   Aab  = (u16*)take((size_t)256 * DM * 2);     // [A_gate;A_up] -> (256, 2048)
  u16*   Adb  = (u16*)take((size_t)128 * DMLP * 2);   // A_down -> (128, 8192)
  float* tdp  = (float*)take((size_t)8 * NTOK * 128 * 4);
  int*   idx  = (int*)take((size_t)NTOK * 4);
  if (off > ws_size) return;

  cvt_kernel<<<64, 256, 0, stream>>>(Ag, Aab, 128 * DM / 4);
  cvt_kernel<<<64, 256, 0, stream>>>(Au, Aab + 128 * DM, 128 * DM / 4);
  cvt_kernel<<<128, 256, 0, stream>>>(Ad, Adb, 128 * DMLP / 4);

  build_wx<<<DMLP, 256, 0, stream>>>(wg, Bg, wgx, DM, LDXA, 0,   DMLP);
  build_wx<<<DMLP, 256, 0, stream>>>(wu, Bu, wux, DM, LDXA, 128, DMLP);
  build_wx<<<DM,   256, 0, stream>>>(wd, Bd, wdx, DMLP, LDHA, 0, DM);

  router_kernel<<<NTOK / 4, 256, 0, stream>>>(x, rw, rb, xa, idx, out_rout, out_ec);

  // t = xa @ [A_gate;A_up]^T -> masked SCAL*t into xa[:, 2048:2304]
  gemm_kernel<0><<<dim3(32, 2), 256, 0, stream>>>(xa, Aab, nullptr, idx, xa);
  // gate/up fused (lora in K) + silu*mul -> ha[:, 0:8192]
  gemm_kernel<1><<<dim3(32, 128), 256, 0, stream>>>(xa, wgx, wux, idx, ha);
  // t_down partials: ha[:, :8192] @ A_down^T, 8-way K-split
  gemm_kernel<3><<<dim3(32, 8), 256, 0, stream>>>(ha, Adb, nullptr, idx, tdp);
  td_reduce<<<NTOK * 128 / 256, 256, 0, stream>>>(tdp, idx, ha);
  // down (lora in K) -> f32 out
  gemm_kernel<2><<<dim3(32, 16), 256, 0, stream>>>(ha, wdx, nullptr, idx, out);
}

// Round 3
// 593.023 us; speedup vs baseline: 1.5931x; 1.1818x over previous
//
#include <hip/hip_runtime.h>
#include <stdint.h>

#define NTOK   4096
#define DM     2048
#define DMLP   8192
#define NEXP   8
#define NRANK  16
#define SCAL   2.0f

// Wide-A strides (LoRA folded into K):
//   xa: [4096, 2304]  = [x_bf16 | SCAL*t_gate_masked(128) | SCAL*t_up_masked(128)]
//   ha: [4096, 8320]  = [h_bf16 | SCAL*t_down_masked(128)]
#define LDXA 2304
#define LDHA 8320

typedef __bf16 bf16x8 __attribute__((ext_vector_type(8)));
typedef float  f32x4  __attribute__((ext_vector_type(4)));
typedef unsigned short u16;

__device__ __forceinline__ u16 f2bf(float f) {
  unsigned u = __float_as_uint(f);
  u += 0x7fffu + ((u >> 16) & 1u);   // RNE
  return (u16)(u >> 16);
}

__device__ __forceinline__ void gload_lds16(const void* g, void* l) {
  __builtin_amdgcn_global_load_lds((const __attribute__((address_space(1))) void*)g,
                                   (__attribute__((address_space(3))) void*)l, 16, 0, 0);
}

// ---------------- generic f32 -> bf16 convert ----------------
__global__ void cvt_kernel(const float* __restrict__ src, u16* __restrict__ dst, int n4) {
  int i = blockIdx.x * blockDim.x + threadIdx.x;
  int stride = gridDim.x * blockDim.x;
  for (; i < n4; i += stride) {
    float4 v = ((const float4*)src)[i];
    ushort4 o;
    o.x = f2bf(v.x); o.y = f2bf(v.y); o.z = f2bf(v.z); o.w = f2bf(v.w);
    ((ushort4*)dst)[i] = o;
  }
}

// ---------------- build extended weight matrices ----------------
__global__ void build_wx(const float* __restrict__ W,
                         const float* __restrict__ Bm,
                         u16* __restrict__ dst,
                         int din, int ldx, int extoff, int browstride) {
  const int o = blockIdx.x;
  const int tid = threadIdx.x;
  u16* drow = dst + (size_t)o * ldx;
  const float* wrow = W + (size_t)o * din;
  for (int c4 = tid; c4 < din / 4; c4 += 256) {
    float4 v = ((const float4*)wrow)[c4];
    ushort4 ov;
    ov.x = f2bf(v.x); ov.y = f2bf(v.y); ov.z = f2bf(v.z); ov.w = f2bf(v.w);
    ((ushort4*)drow)[c4] = ov;
  }
  const int next = ldx - din;
  if (tid < next) {
    int c = tid;
    u16 val = 0;
    if (c >= extoff && c < extoff + NEXP * NRANK) {
      int ce = c - extoff;
      int e = ce >> 4, r = ce & 15;
      val = f2bf(Bm[((size_t)e * browstride + o) * NRANK + r]);
    }
    drow[din + c] = val;
  }
}

// ---------------- router ----------------
__global__ void router_kernel(const float* __restrict__ x,
                              const float* __restrict__ rw,
                              const float* __restrict__ rb,
                              u16* __restrict__ xa,
                              int* __restrict__ idx,
                              float* __restrict__ out_rout,
                              float* __restrict__ out_ec) {
  const int wave = threadIdx.x >> 6;
  const int lane = threadIdx.x & 63;
  const int m = blockIdx.x * 4 + wave;

  const float4* xrow = (const float4*)(x + (size_t)m * DM + lane * 32);
  float4 xv[8];
#pragma unroll
  for (int i = 0; i < 8; ++i) xv[i] = xrow[i];

  uint4 o[4];
  unsigned* op = (unsigned*)o;
#pragma unroll
  for (int i = 0; i < 8; ++i) {
    op[2*i]   = (unsigned)f2bf(xv[i].x) | ((unsigned)f2bf(xv[i].y) << 16);
    op[2*i+1] = (unsigned)f2bf(xv[i].z) | ((unsigned)f2bf(xv[i].w) << 16);
  }
  uint4* xdst = (uint4*)(xa + (size_t)m * LDXA + lane * 32);
#pragma unroll
  for (int i = 0; i < 4; ++i) xdst[i] = o[i];

  float lg[NEXP];
#pragma unroll
  for (int e = 0; e < NEXP; ++e) {
    const float4* wrow = (const float4*)(rw + (size_t)e * DM + lane * 32);
    float s = 0.f;
#pragma unroll
    for (int i = 0; i < 8; ++i) {
      float4 wv = wrow[i];
      s += xv[i].x*wv.x + xv[i].y*wv.y + xv[i].z*wv.z + xv[i].w*wv.w;
    }
#pragma unroll
    for (int off = 32; off > 0; off >>= 1) s += __shfl_xor(s, off, 64);
    lg[e] = s + rb[e];
  }

  float mx = lg[0];
#pragma unroll
  for (int e = 1; e < NEXP; ++e) mx = fmaxf(mx, lg[e]);
  float ex[NEXP], se = 0.f;
#pragma unroll
  for (int e = 0; e < NEXP; ++e) { ex[e] = expf(lg[e] - mx); se += ex[e]; }
  float inv = 1.f / se;
  int best = 0; float bv = lg[0];
#pragma unroll
  for (int e = 1; e < NEXP; ++e) if (lg[e] > bv) { bv = lg[e]; best = e; }

  if (lane == 0) {
    idx[m] = best;
#pragma unroll
    for (int e = 0; e < NEXP; ++e) {
      float r = ex[e] * inv;
      out_rout[(size_t)m * NEXP + e] = r;
      float hard = (e == best) ? 1.f : 0.f;
      out_ec[(size_t)m * NEXP + e] = (hard - r) + r;
    }
  }
}

// ---------------- old 128x128 GEMM core (kept for small MODE 0 / MODE 3) ----------------
template<int MODE>
__global__ __launch_bounds__(256, 2)
void gemm_kernel(const u16* __restrict__ A,
                 const u16* __restrict__ B0,
                 const int* __restrict__ idx,
                 void* __restrict__ Cout)
{
  constexpr int LDA = (MODE == 0) ? LDXA : LDHA;
  constexpr int LDB = (MODE == 0) ? 2048 : 8192;
  constexpr int NKI = (MODE == 0) ? 64 : 32;

  __shared__ u16 lds[16384];

  const int tid = threadIdx.x;
  const int w = tid >> 6;
  const int l = tid & 63;
  const int wm = w >> 1, wn = w & 1;
  const int mtile = blockIdx.x;
  const int ntile = (MODE == 3) ? 0 : (int)blockIdx.y;
  const int ks    = (MODE == 3) ? (int)blockIdx.y : 0;
  const int kb0   = (MODE == 3) ? ks * 1024 : 0;

  int srow[2];
  srow[0] = w * 16 + (l >> 2);
  srow[1] = 64 + srow[0];
  const int chunk = (l & 3) ^ ((srow[0] >> 1) & 3);
  const int scol = chunk * 8;

  const u16* aptr[2];
  const u16* bptr[2];
#pragma unroll
  for (int i = 0; i < 2; ++i) {
    aptr[i] = A + (size_t)(mtile * 128 + srow[i]) * LDA + kb0 + scol;
    bptr[i] = B0 + (size_t)(ntile * 128 + srow[i]) * LDB + kb0 + scol;
  }

  char* ldsc = (char*)lds;
  auto stage = [&](int buf, int kt) {
    const int kk = kt * 32;
    char* base = ldsc + buf * 16384;
#pragma unroll
    for (int i = 0; i < 2; ++i) {
      gload_lds16(aptr[i] + kk, base + i * 4096 + w * 1024);
      gload_lds16(bptr[i] + kk, base + 8192 + i * 4096 + w * 1024);
    }
  };

  f32x4 acc[4][4];
  f32x4 zf = {0.f, 0.f, 0.f, 0.f};
#pragma unroll
  for (int a = 0; a < 4; ++a)
#pragma unroll
    for (int b = 0; b < 4; ++b) acc[a][b] = zf;

  stage(0, 0);
  __syncthreads();

  const int kq   = l >> 4;
  const int arow = wm * 64 + (l & 15);
  const int brow = wn * 64 + (l & 15);
  const int axor = (kq ^ ((arow >> 1) & 3)) << 4;
  const int bxor = (kq ^ ((brow >> 1) & 3)) << 4;

  for (int kt = 0; kt < NKI; ++kt) {
    const int buf = kt & 1;
    if (kt + 1 < NKI) stage(buf ^ 1, kt + 1);
    const char* bA = ldsc + buf * 16384;
    const char* bB = bA + 8192;
    bf16x8 af[4], bfr[4];
#pragma unroll
    for (int fm = 0; fm < 4; ++fm)
      af[fm] = *(const bf16x8*)(bA + (arow + fm * 16) * 64 + axor);
#pragma unroll
    for (int fn = 0; fn < 4; ++fn)
      bfr[fn] = *(const bf16x8*)(bB + (brow + fn * 16) * 64 + bxor);
#pragma unroll
    for (int fm = 0; fm < 4; ++fm)
#pragma unroll
      for (int fn = 0; fn < 4; ++fn)
        acc[fm][fn] = __builtin_amdgcn_mfma_f32_16x16x32_bf16(af[fm], bfr[fn], acc[fm][fn], 0, 0, 0);
    __syncthreads();
  }

  const int lq = l >> 4;
  const int lr = l & 15;

  if (MODE == 0) {
    u16* X = (u16*)Cout;
#pragma unroll
    for (int fm = 0; fm < 4; ++fm)
#pragma unroll
      for (int fn = 0; fn < 4; ++fn)
        for (int j = 0; j < 4; ++j) {
          int m = mtile * 128 + wm * 64 + fm * 16 + lq * 4 + j;
          int c = ntile * 128 + wn * 64 + fn * 16 + lr;
          int e = idx[m];
          u16 v = (((c & 127) >> 4) == e) ? f2bf(SCAL * acc[fm][fn][j]) : (u16)0;
          X[(size_t)m * LDXA + 2048 + c] = v;
        }
  } else {
    float* P = (float*)Cout + (size_t)ks * NTOK * 128;
#pragma unroll
    for (int fm = 0; fm < 4; ++fm)
#pragma unroll
      for (int fn = 0; fn < 4; ++fn)
        for (int j = 0; j < 4; ++j) {
          int m = mtile * 128 + wm * 64 + fm * 16 + lq * 4 + j;
          int c = wn * 64 + fn * 16 + lr;
          P[(size_t)m * 128 + c] = acc[fm][fn][j];
        }
  }
}

// ---------------- 8-phase deep-pipelined GEMM (256-col tile, BK=64, 512 thr, 8 waves 2x4) ----
// M8==1: gate/up fused (A=xa K=2304, B=wgx/wux interleaved) + silu*mul -> ha bf16
// M8==2: down (A=ha K=8320, B=wdx) -> f32 out [BM=128 so grid = 32x8 = 256 blocks]
// LDS: A 2buf x 2slice x (BM*64)B + B 2x2x16KB. Slice = 32 k-elems (one MFMA k-substep).
// Swizzle: phys_chunk(16B) = logic_chunk ^ ((row>>1)&3), applied via pre-swizzled global
// source on stage (linear LDS dest) and XOR'd read address (rule #21; measured 0 conflicts r2).
template<int BM, int NKT, int LDA, int LDB, int M8>
__global__ __launch_bounds__(512, 2)
void gemm8(const u16* __restrict__ Ag,
           const u16* __restrict__ B0g,
           const u16* __restrict__ B1g,
           void* __restrict__ Cout)
{
  constexpr int FM  = BM / 32;        // fm frags per wave (8 or 4)
  constexpr int FH  = FM / 2;         // frags per qa-half
  constexpr int APL = BM / 128;       // A gload instrs per slice (2 or 1)
  constexpr int ASL = BM * 64;        // A slice bytes (16K or 8K)
  constexpr int NIT = NKT / 2;
  constexpr int NTILES = (M8 == 1) ? 64 : 8;
  constexpr int NWG    = (M8 == 1) ? 1024 : 256;

  __shared__ char lds8[4 * ASL + 65536];

  const int tid = threadIdx.x;
  const int w = tid >> 6, l = tid & 63;
  const int wm = w >> 2, wn = w & 3;

  // XCD-aware bijective swizzle (NWG % 8 == 0)
  const int bid = blockIdx.x;
  const int swz = (bid & 7) * (NWG / 8) + (bid >> 3);
  const int mtile = swz / NTILES;
  const int ntile = swz % NTILES;

  auto stage_a = [&](int buf, int s, int kt) {
    int ktc = kt < NKT - 1 ? kt : NKT - 1;
#pragma unroll
    for (int i = 0; i < APL; ++i) {
      int row = i * 128 + (tid >> 2);
      int lc  = (tid & 3) ^ ((row >> 1) & 3);
      const u16* g = Ag + (size_t)(mtile * BM + row) * LDA + ktc * 64 + s * 32 + lc * 8;
      char* lp = lds8 + (buf * 2 + s) * ASL + i * 8192 + w * 1024;  // wave-uniform
      gload_lds16(g, lp);
    }
  };
  auto stage_b = [&](int buf, int s, int kt) {
    int ktc = kt < NKT - 1 ? kt : NKT - 1;
#pragma unroll
    for (int i = 0; i < 2; ++i) {
      int row = i * 128 + (tid >> 2);
      int lc  = (tid & 3) ^ ((row >> 1) & 3);
      const u16* src;
      size_t roff;
      if (M8 == 1) {
        int c = ntile * 128 + ((row >> 5) << 4) + (row & 15);
        src = ((row >> 4) & 1) ? B1g : B0g;
        roff = (size_t)c * LDB;
      } else {
        src = B0g;
        roff = (size_t)(ntile * 256 + row) * LDB;
      }
      const u16* g = src + roff + ktc * 64 + s * 32 + lc * 8;
      char* lp = lds8 + 4 * ASL + (buf * 2 + s) * 16384 + i * 8192 + w * 1024;
      gload_lds16(g, lp);
    }
  };

  const int lr  = l & 15;
  const int kqp = l >> 4;
  const int ko  = ((kqp ^ ((lr >> 1) & 3)) << 4);   // swizzled phys chunk byte

  bf16x8 a4[FH], b4[4];
  f32x4 acc[FM][4];
  f32x4 zf = {0.f, 0.f, 0.f, 0.f};
#pragma unroll
  for (int a = 0; a < FM; ++a)
#pragma unroll
    for (int b = 0; b < 4; ++b) acc[a][b] = zf;

  auto readA = [&](int buf, int s, int qa) {
#pragma unroll
    for (int f = 0; f < FH; ++f) {
      int row = wm * (BM / 2) + (qa * FH + f) * 16 + lr;
      a4[f] = *(const bf16x8*)(lds8 + (buf * 2 + s) * ASL + row * 64 + ko);
    }
  };
  auto readB = [&](int buf, int s) {
#pragma unroll
    for (int f = 0; f < 4; ++f) {
      int row = wn * 64 + f * 16 + lr;
      b4[f] = *(const bf16x8*)(lds8 + 4 * ASL + (buf * 2 + s) * 16384 + row * 64 + ko);
    }
  };
  auto waitvm = [&] {
    if constexpr (BM == 256) asm volatile("s_waitcnt vmcnt(8)" ::: "memory");
    else                     asm volatile("s_waitcnt vmcnt(6)" ::: "memory");
  };

#define MFMA_Q(qa) \
  _Pragma("unroll") \
  for (int f = 0; f < FH; ++f) \
    _Pragma("unroll") \
    for (int n = 0; n < 4; ++n) \
      acc[(qa) * FH + f][n] = \
        __builtin_amdgcn_mfma_f32_16x16x32_bf16(a4[f], b4[n], acc[(qa) * FH + f][n], 0, 0, 0);

#define PHASE(cb, s, qa, STG, doVM) \
  { if ((qa) == 0) readB(cb, s); \
    readA(cb, s, qa); \
    STG; \
    __builtin_amdgcn_sched_barrier(0); \
    __builtin_amdgcn_s_barrier(); \
    asm volatile("s_waitcnt lgkmcnt(0)" ::: "memory"); \
    __builtin_amdgcn_sched_barrier(0); \
    __builtin_amdgcn_s_setprio(1); \
    MFMA_Q(qa); \
    __builtin_amdgcn_s_setprio(0); \
    __builtin_amdgcn_sched_barrier(0); \
    if (doVM) { waitvm(); __builtin_amdgcn_sched_barrier(0); } \
    __builtin_amdgcn_s_barrier(); }

  // Prologue: kt0 both slices + kt1 slice0; drain oldest slice (vmcnt leaves newest 8/6)
  stage_a(0, 0, 0); stage_b(0, 0, 0);
  stage_a(0, 1, 0); stage_b(0, 1, 0);
  stage_a(1, 0, 1); stage_b(1, 0, 1);
  waitvm();
  __builtin_amdgcn_sched_barrier(0);
  __builtin_amdgcn_s_barrier();

  for (int it = 0; it < NIT; ++it) {
    const int k1 = 2 * it + 1, k2 = 2 * it + 2, k3 = 2 * it + 3;
    PHASE(0, 0, 0, stage_a(1, 1, k1), 0)
    PHASE(0, 0, 1, stage_b(1, 1, k1), 1)
    PHASE(0, 1, 0, stage_a(0, 0, k2), 0)
    PHASE(0, 1, 1, stage_b(0, 0, k2), 1)
    PHASE(1, 0, 0, stage_a(0, 1, k2), 0)
    PHASE(1, 0, 1, stage_b(0, 1, k2), 1)
    PHASE(1, 1, 0, stage_a(1, 0, k3), 0)
    PHASE(1, 1, 1, stage_b(1, 0, k3), 1)
  }

  const int lq = l >> 4;
  if (M8 == 1) {
    u16* H = (u16*)Cout;
#pragma unroll
    for (int fm = 0; fm < FM; ++fm)
      for (int jj = 0; jj < 4; ++jj) {
        const int m = mtile * 256 + wm * 128 + fm * 16 + lq * 4 + jj;
#pragma unroll
        for (int p = 0; p < 2; ++p) {
          float g = acc[fm][2 * p][jj];
          float u = acc[fm][2 * p + 1][jj];
          float h = g / (1.f + __expf(-g)) * u;
          const int c = ntile * 128 + (wn * 2 + p) * 16 + lr;
          H[(size_t)m * LDHA + c] = f2bf(h);
        }
      }
  } else {
    float* C = (float*)Cout;
#pragma unroll
    for (int fm = 0; fm < FM; ++fm)
#pragma unroll
      for (int n = 0; n < 4; ++n)
        for (int jj = 0; jj < 4; ++jj) {
          const int m = mtile * 128 + wm * 64 + fm * 16 + lq * 4 + jj;
          const int c = ntile * 256 + wn * 64 + n * 16 + lr;
          C[(size_t)m * DM + c] = acc[fm][n][jj];
        }
  }
#undef PHASE
#undef MFMA_Q
}

// ---------------- t_down split-K reduce -> masked SCAL*td into ha ext cols ----------------
__global__ void td_reduce(const float* __restrict__ part,
                          const int* __restrict__ idx,
                          u16* __restrict__ ha) {
  int i = blockIdx.x * blockDim.x + threadIdx.x;
  int m = i >> 7, c = i & 127;
  float s = 0.f;
#pragma unroll
  for (int k = 0; k < 8; ++k) s += part[(size_t)k * NTOK * 128 + i];
  u16 v = ((c >> 4) == idx[m]) ? f2bf(SCAL * s) : (u16)0;
  ha[(size_t)m * LDHA + 8192 + c] = v;
}

extern "C" void kernel_launch(void* const* d_in, const int* in_sizes, int n_in,
                              void* d_out, int out_size, void* d_ws, size_t ws_size,
                              hipStream_t stream) {
  const float* x  = (const float*)d_in[0];
  const float* wg = (const float*)d_in[1];
  const float* wu = (const float*)d_in[2];
  const float* wd = (const float*)d_in[3];
  const float* rw = (const float*)d_in[4];
  const float* rb = (const float*)d_in[5];
  const float* Ag = (const float*)d_in[6];
  const float* Bg = (const float*)d_in[7];
  const float* Au = (const float*)d_in[8];
  const float* Bu = (const float*)d_in[9];
  const float* Ad = (const float*)d_in[10];
  const float* Bd = (const float*)d_in[11];

  float* out      = (float*)d_out;
  float* out_rout = out + (size_t)NTOK * DM;
  float* out_ec   = out_rout + (size_t)NTOK * NEXP;

  char* ws = (char*)d_ws;
  size_t off = 0;
  auto take = [&](size_t b) { void* p = ws + off; off += (b + 255) & ~(size_t)255; return p; };
  u16*   xa   = (u16*)take((size_t)NTOK * LDXA * 2);
  u16*   ha   = (u16*)take((size_t)NTOK * LDHA * 2);
  u16*   wgx  = (u16*)take((size_t)DMLP * LDXA * 2);
  u16*   wux  = (u16*)take((size_t)DMLP * LDXA * 2);
  u16*   wdx  = (u16*)take((size_t)DM * LDHA * 2);
  u16*   Aab  = (u16*)take((size_t)256 * DM * 2);
  u16*   Adb  = (u16*)take((size_t)128 * DMLP * 2);
  float* tdp  = (float*)take((size_t)8 * NTOK * 128 * 4);
  int*   idx  = (int*)take((size_t)NTOK * 4);
  if (off > ws_size) return;

  cvt_kernel<<<64, 256, 0, stream>>>(Ag, Aab, 128 * DM / 4);
  cvt_kernel<<<64, 256, 0, stream>>>(Au, Aab + 128 * DM, 128 * DM / 4);
  cvt_kernel<<<128, 256, 0, stream>>>(Ad, Adb, 128 * DMLP / 4);

  build_wx<<<DMLP, 256, 0, stream>>>(wg, Bg, wgx, DM, LDXA, 0,   DMLP);
  build_wx<<<DMLP, 256, 0, stream>>>(wu, Bu, wux, DM, LDXA, 128, DMLP);
  build_wx<<<DM,   256, 0, stream>>>(wd, Bd, wdx, DMLP, LDHA, 0, DM);

  router_kernel<<<NTOK / 4, 256, 0, stream>>>(x, rw, rb, xa, idx, out_rout, out_ec);

  // t = xa @ [A_gate;A_up]^T -> masked SCAL*t into xa[:, 2048:2304]
  gemm_kernel<0><<<dim3(32, 2), 256, 0, stream>>>(xa, Aab, idx, xa);
  // gate/up fused (lora in K) + silu*mul -> ha[:, 0:8192]   [8-phase 256x256]
  gemm8<256, 36, LDXA, LDXA, 1><<<1024, 512, 0, stream>>>(xa, wgx, wux, ha);
  // t_down partials: ha[:, :8192] @ A_down^T, 8-way K-split
  gemm_kernel<3><<<dim3(32, 8), 256, 0, stream>>>(ha, Adb, idx, tdp);
  td_reduce<<<NTOK * 128 / 256, 256, 0, stream>>>(tdp, idx, ha);
  // down (lora in K) -> f32 out   [8-phase 128x256, 256 blocks]
  gemm8<128, 130, LDHA, LDHA, 2><<<256, 512, 0, stream>>>(ha, wdx, nullptr, out);
}

// Round 4
// 574.702 us; speedup vs baseline: 1.6439x; 1.0319x over previous
//
#include <hip/hip_runtime.h>
#include <stdint.h>

#define NTOK   4096
#define DM     2048
#define DMLP   8192
#define NEXP   8
#define NRANK  16
#define SCAL   2.0f

// Wide-A strides (LoRA folded into K):
//   xa: [4096, 2304]  = [x_bf16 | SCAL*t_gate_masked(128) | SCAL*t_up_masked(128)]
//   ha: [4096, 8320]  = [h_bf16 | SCAL*t_down_masked(128)]
#define LDXA 2304
#define LDHA 8320

typedef __bf16 bf16x8 __attribute__((ext_vector_type(8)));
typedef float  f32x4  __attribute__((ext_vector_type(4)));
typedef unsigned short u16;

__device__ __forceinline__ u16 f2bf(float f) {
  unsigned u = __float_as_uint(f);
  u += 0x7fffu + ((u >> 16) & 1u);   // RNE
  return (u16)(u >> 16);
}

__device__ __forceinline__ void gload_lds16(const void* g, void* l) {
  __builtin_amdgcn_global_load_lds((const __attribute__((address_space(1))) void*)g,
                                   (__attribute__((address_space(3))) void*)l, 16, 0, 0);
}

// ---------------- generic f32 -> bf16 convert ----------------
__global__ void cvt_kernel(const float* __restrict__ src, u16* __restrict__ dst, int n4) {
  int i = blockIdx.x * blockDim.x + threadIdx.x;
  int stride = gridDim.x * blockDim.x;
  for (; i < n4; i += stride) {
    float4 v = ((const float4*)src)[i];
    ushort4 o;
    o.x = f2bf(v.x); o.y = f2bf(v.y); o.z = f2bf(v.z); o.w = f2bf(v.w);
    ((ushort4*)dst)[i] = o;
  }
}

// ---------------- build extended weight matrices ----------------
__global__ void build_wx(const float* __restrict__ W,
                         const float* __restrict__ Bm,
                         u16* __restrict__ dst,
                         int din, int ldx, int extoff, int browstride) {
  const int o = blockIdx.x;
  const int tid = threadIdx.x;
  u16* drow = dst + (size_t)o * ldx;
  const float* wrow = W + (size_t)o * din;
  for (int c4 = tid; c4 < din / 4; c4 += 256) {
    float4 v = ((const float4*)wrow)[c4];
    ushort4 ov;
    ov.x = f2bf(v.x); ov.y = f2bf(v.y); ov.z = f2bf(v.z); ov.w = f2bf(v.w);
    ((ushort4*)drow)[c4] = ov;
  }
  const int next = ldx - din;
  if (tid < next) {
    int c = tid;
    u16 val = 0;
    if (c >= extoff && c < extoff + NEXP * NRANK) {
      int ce = c - extoff;
      int e = ce >> 4, r = ce & 15;
      val = f2bf(Bm[((size_t)e * browstride + o) * NRANK + r]);
    }
    drow[din + c] = val;
  }
}

// ---------------- router ----------------
__global__ void router_kernel(const float* __restrict__ x,
                              const float* __restrict__ rw,
                              const float* __restrict__ rb,
                              u16* __restrict__ xa,
                              int* __restrict__ idx,
                              float* __restrict__ out_rout,
                              float* __restrict__ out_ec) {
  const int wave = threadIdx.x >> 6;
  const int lane = threadIdx.x & 63;
  const int m = blockIdx.x * 4 + wave;

  const float4* xrow = (const float4*)(x + (size_t)m * DM + lane * 32);
  float4 xv[8];
#pragma unroll
  for (int i = 0; i < 8; ++i) xv[i] = xrow[i];

  uint4 o[4];
  unsigned* op = (unsigned*)o;
#pragma unroll
  for (int i = 0; i < 8; ++i) {
    op[2*i]   = (unsigned)f2bf(xv[i].x) | ((unsigned)f2bf(xv[i].y) << 16);
    op[2*i+1] = (unsigned)f2bf(xv[i].z) | ((unsigned)f2bf(xv[i].w) << 16);
  }
  uint4* xdst = (uint4*)(xa + (size_t)m * LDXA + lane * 32);
#pragma unroll
  for (int i = 0; i < 4; ++i) xdst[i] = o[i];

  float lg[NEXP];
#pragma unroll
  for (int e = 0; e < NEXP; ++e) {
    const float4* wrow = (const float4*)(rw + (size_t)e * DM + lane * 32);
    float s = 0.f;
#pragma unroll
    for (int i = 0; i < 8; ++i) {
      float4 wv = wrow[i];
      s += xv[i].x*wv.x + xv[i].y*wv.y + xv[i].z*wv.z + xv[i].w*wv.w;
    }
#pragma unroll
    for (int off = 32; off > 0; off >>= 1) s += __shfl_xor(s, off, 64);
    lg[e] = s + rb[e];
  }

  float mx = lg[0];
#pragma unroll
  for (int e = 1; e < NEXP; ++e) mx = fmaxf(mx, lg[e]);
  float ex[NEXP], se = 0.f;
#pragma unroll
  for (int e = 0; e < NEXP; ++e) { ex[e] = expf(lg[e] - mx); se += ex[e]; }
  float inv = 1.f / se;
  int best = 0; float bv = lg[0];
#pragma unroll
  for (int e = 1; e < NEXP; ++e) if (lg[e] > bv) { bv = lg[e]; best = e; }

  if (lane == 0) {
    idx[m] = best;
#pragma unroll
    for (int e = 0; e < NEXP; ++e) {
      float r = ex[e] * inv;
      out_rout[(size_t)m * NEXP + e] = r;
      float hard = (e == best) ? 1.f : 0.f;
      out_ec[(size_t)m * NEXP + e] = (hard - r) + r;
    }
  }
}

// ---------------- old 128x128 GEMM core (small MODE 0 / MODE 3) ----------------
template<int MODE>
__global__ __launch_bounds__(256, 2)
void gemm_kernel(const u16* __restrict__ A,
                 const u16* __restrict__ B0,
                 const int* __restrict__ idx,
                 void* __restrict__ Cout)
{
  constexpr int LDA = (MODE == 0) ? LDXA : LDHA;
  constexpr int LDB = (MODE == 0) ? 2048 : 8192;
  constexpr int NKI = (MODE == 0) ? 64 : 32;

  __shared__ u16 lds[16384];

  const int tid = threadIdx.x;
  const int w = tid >> 6;
  const int l = tid & 63;
  const int wm = w >> 1, wn = w & 1;
  const int mtile = blockIdx.x;
  const int ntile = (MODE == 3) ? 0 : (int)blockIdx.y;
  const int ks    = (MODE == 3) ? (int)blockIdx.y : 0;
  const int kb0   = (MODE == 3) ? ks * 1024 : 0;

  int srow[2];
  srow[0] = w * 16 + (l >> 2);
  srow[1] = 64 + srow[0];
  const int chunk = (l & 3) ^ ((srow[0] >> 1) & 3);
  const int scol = chunk * 8;

  const u16* aptr[2];
  const u16* bptr[2];
#pragma unroll
  for (int i = 0; i < 2; ++i) {
    aptr[i] = A + (size_t)(mtile * 128 + srow[i]) * LDA + kb0 + scol;
    bptr[i] = B0 + (size_t)(ntile * 128 + srow[i]) * LDB + kb0 + scol;
  }

  char* ldsc = (char*)lds;
  auto stage = [&](int buf, int kt) {
    const int kk = kt * 32;
    char* base = ldsc + buf * 16384;
#pragma unroll
    for (int i = 0; i < 2; ++i) {
      gload_lds16(aptr[i] + kk, base + i * 4096 + w * 1024);
      gload_lds16(bptr[i] + kk, base + 8192 + i * 4096 + w * 1024);
    }
  };

  f32x4 acc[4][4];
  f32x4 zf = {0.f, 0.f, 0.f, 0.f};
#pragma unroll
  for (int a = 0; a < 4; ++a)
#pragma unroll
    for (int b = 0; b < 4; ++b) acc[a][b] = zf;

  stage(0, 0);
  __syncthreads();

  const int kq   = l >> 4;
  const int arow = wm * 64 + (l & 15);
  const int brow = wn * 64 + (l & 15);
  const int axor = (kq ^ ((arow >> 1) & 3)) << 4;
  const int bxor = (kq ^ ((brow >> 1) & 3)) << 4;

  for (int kt = 0; kt < NKI; ++kt) {
    const int buf = kt & 1;
    if (kt + 1 < NKI) stage(buf ^ 1, kt + 1);
    const char* bA = ldsc + buf * 16384;
    const char* bB = bA + 8192;
    bf16x8 af[4], bfr[4];
#pragma unroll
    for (int fm = 0; fm < 4; ++fm)
      af[fm] = *(const bf16x8*)(bA + (arow + fm * 16) * 64 + axor);
#pragma unroll
    for (int fn = 0; fn < 4; ++fn)
      bfr[fn] = *(const bf16x8*)(bB + (brow + fn * 16) * 64 + bxor);
#pragma unroll
    for (int fm = 0; fm < 4; ++fm)
#pragma unroll
      for (int fn = 0; fn < 4; ++fn)
        acc[fm][fn] = __builtin_amdgcn_mfma_f32_16x16x32_bf16(af[fm], bfr[fn], acc[fm][fn], 0, 0, 0);
    __syncthreads();
  }

  const int lq = l >> 4;
  const int lr = l & 15;

  if (MODE == 0) {
    u16* X = (u16*)Cout;
#pragma unroll
    for (int fm = 0; fm < 4; ++fm)
#pragma unroll
      for (int fn = 0; fn < 4; ++fn)
        for (int j = 0; j < 4; ++j) {
          int m = mtile * 128 + wm * 64 + fm * 16 + lq * 4 + j;
          int c = ntile * 128 + wn * 64 + fn * 16 + lr;
          int e = idx[m];
          u16 v = (((c & 127) >> 4) == e) ? f2bf(SCAL * acc[fm][fn][j]) : (u16)0;
          X[(size_t)m * LDXA + 2048 + c] = v;
        }
  } else {
    float* P = (float*)Cout + (size_t)ks * NTOK * 128;
#pragma unroll
    for (int fm = 0; fm < 4; ++fm)
#pragma unroll
      for (int fn = 0; fn < 4; ++fn)
        for (int j = 0; j < 4; ++j) {
          int m = mtile * 128 + wm * 64 + fm * 16 + lq * 4 + j;
          int c = wn * 64 + fn * 16 + lr;
          P[(size_t)m * 128 + c] = acc[fm][fn][j];
        }
  }
}

// ---------------- 8/4-phase deep-pipelined GEMM (BN=256, BK=64, 512 thr, 8 waves 2x4) ----
// M8==1: BM=256, gate/up fused (A=xa K=2304, B=wgx/wux interleaved) + silu*mul -> ha bf16
// M8==2: BM=128, down (A=ha K=8320, B=wdx) -> f32 out  [4-phase, 16-MFMA phases]
// Swizzle: phys 16B chunk = logic chunk ^ ((row>>1)&3), via pre-swizzled global source on
// stage (linear LDS dest) + XOR'd read address (rule #21; measured 0 conflicts r2/r3).
template<int BM, int NKT, int LDA, int LDB, int M8>
__global__ __launch_bounds__(512, 2)
void gemm8(const u16* __restrict__ Ag,
           const u16* __restrict__ B0g,
           const u16* __restrict__ B1g,
           void* __restrict__ Cout)
{
  constexpr int FM  = BM / 32;        // acc frag rows per wave (8 or 4)
  constexpr int QP  = (BM == 256) ? 2 : 1;  // qa sub-phases per slice
  constexpr int APL = BM / 128;       // A gloads per slice (2 or 1)
  constexpr int ASL = BM * 64;        // A slice bytes (16K or 8K)
  constexpr int NIT = NKT / 2;

  __shared__ char lds8[4 * ASL + 65536];

  const int tid = threadIdx.x;
  const int w = tid >> 6, l = tid & 63;
  const int wm = w >> 2, wn = w & 3;

  // XCD-grouped 2D mapping (each XCD gets a 2D chunk -> B panels L2-resident)
  const int bid = blockIdx.x;
  int mtile, ntile;
  if (M8 == 1) {            // 1024 wgs = 16 mtiles x 64 ntiles; XCD chunk = 4m x 8n
    int r = bid >> 3;
    mtile = r >> 3;
    ntile = (bid & 7) * 8 + (r & 7);
  } else {                  // 256 wgs = 32 mtiles x 8 ntiles; XCD chunk = 4m x 8n
    int swz = (bid & 7) * 32 + (bid >> 3);
    mtile = swz >> 3;
    ntile = swz & 7;
  }

  // ---- hoisted per-thread global base pointers (k=0, swizzled chunk folded in) ----
  const u16* agb[APL];
  const u16* bgb[2];
#pragma unroll
  for (int i = 0; i < APL; ++i) {
    int row = i * 128 + (tid >> 2);
    int lc  = (tid & 3) ^ ((row >> 1) & 3);
    agb[i] = Ag + (size_t)(mtile * BM + row) * LDA + lc * 8;
  }
#pragma unroll
  for (int i = 0; i < 2; ++i) {
    int row = i * 128 + (tid >> 2);
    int lc  = (tid & 3) ^ ((row >> 1) & 3);
    if (M8 == 1) {
      int c = ntile * 128 + ((row >> 5) << 4) + (row & 15);
      bgb[i] = (((row >> 4) & 1) ? B1g : B0g) + (size_t)c * LDB + lc * 8;
    } else {
      bgb[i] = B0g + (size_t)(ntile * 256 + row) * LDB + lc * 8;
    }
  }

  auto stage_a = [&](int buf, int s, int kt) {
    const int ko = (kt < NKT - 1 ? kt : NKT - 1) * 64 + s * 32;   // uniform (SALU)
#pragma unroll
    for (int i = 0; i < APL; ++i)
      gload_lds16(agb[i] + ko, lds8 + (buf * 2 + s) * ASL + i * 8192 + w * 1024);
  };
  auto stage_b = [&](int buf, int s, int kt) {
    const int ko = (kt < NKT - 1 ? kt : NKT - 1) * 64 + s * 32;
#pragma unroll
    for (int i = 0; i < 2; ++i)
      gload_lds16(bgb[i] + ko, lds8 + 4 * ASL + (buf * 2 + s) * 16384 + i * 8192 + w * 1024);
  };

  // ---- hoisted LDS read offsets ----
  const int lr  = l & 15;
  const int kob = ((l >> 4) ^ ((lr >> 1) & 3)) << 4;   // swizzled phys chunk byte
  int aoff[QP][4];
#pragma unroll
  for (int qa = 0; qa < QP; ++qa)
#pragma unroll
    for (int f = 0; f < 4; ++f)
      aoff[qa][f] = (wm * (BM / 2) + (qa * 4 + f) * 16 + lr) * 64 + kob;
  int boff[4];
#pragma unroll
  for (int f = 0; f < 4; ++f)
    boff[f] = (wn * 64 + f * 16 + lr) * 64 + kob;

  bf16x8 a4[4], b4[4];
  f32x4 acc[FM][4];
  f32x4 zf = {0.f, 0.f, 0.f, 0.f};
#pragma unroll
  for (int a = 0; a < FM; ++a)
#pragma unroll
    for (int b = 0; b < 4; ++b) acc[a][b] = zf;

  auto readA = [&](int buf, int s, int qa) {
#pragma unroll
    for (int f = 0; f < 4; ++f)
      a4[f] = *(const bf16x8*)(lds8 + (buf * 2 + s) * ASL + aoff[qa][f]);
  };
  auto readB = [&](int buf, int s) {
#pragma unroll
    for (int f = 0; f < 4; ++f)
      b4[f] = *(const bf16x8*)(lds8 + 4 * ASL + (buf * 2 + s) * 16384 + boff[f]);
  };
  auto waitvm = [&] {
    if constexpr (BM == 256) asm volatile("s_waitcnt vmcnt(8)" ::: "memory");
    else                     asm volatile("s_waitcnt vmcnt(6)" ::: "memory");
  };

#define MFMA_Q(qa) \
  _Pragma("unroll") \
  for (int f = 0; f < 4; ++f) \
    _Pragma("unroll") \
    for (int n = 0; n < 4; ++n) \
      acc[(qa) * 4 + f][n] = \
        __builtin_amdgcn_mfma_f32_16x16x32_bf16(a4[f], b4[n], acc[(qa) * 4 + f][n], 0, 0, 0);

// fine-grained lgkmcnt left to the compiler (per-use waits); raw barriers do not drain
#define PHASE(cb, s, qa, STG, doVM) \
  { STG; \
    if ((qa) == 0) readB(cb, s); \
    readA(cb, s, qa); \
    __builtin_amdgcn_s_barrier(); \
    __builtin_amdgcn_s_setprio(1); \
    MFMA_Q(qa); \
    __builtin_amdgcn_s_setprio(0); \
    if (doVM) { waitvm(); __builtin_amdgcn_sched_barrier(0); } \
    __builtin_amdgcn_s_barrier(); }

  if constexpr (BM == 256) {
    // prologue: 12 loads, drain oldest slice-pair (vmcnt 8)
    stage_a(0, 0, 0); stage_b(0, 0, 0);
    stage_a(0, 1, 0); stage_b(0, 1, 0);
    stage_a(1, 0, 1); stage_b(1, 0, 1);
    waitvm();
    __builtin_amdgcn_sched_barrier(0);
    __builtin_amdgcn_s_barrier();
    for (int it = 0; it < NIT; ++it) {
      const int k1 = 2 * it + 1, k2 = 2 * it + 2, k3 = 2 * it + 3;
      PHASE(0, 0, 0, stage_a(1, 1, k1), 0)
      PHASE(0, 0, 1, stage_b(1, 1, k1), 1)
      PHASE(0, 1, 0, stage_a(0, 0, k2), 0)
      PHASE(0, 1, 1, stage_b(0, 0, k2), 1)
      PHASE(1, 0, 0, stage_a(0, 1, k2), 0)
      PHASE(1, 0, 1, stage_b(0, 1, k2), 1)
      PHASE(1, 1, 0, stage_a(1, 0, k3), 0)
      PHASE(1, 1, 1, stage_b(1, 0, k3), 1)
    }
  } else {
    // 4-phase: each phase = full slice (16 MFMA), stage one slice-pair (3 loads),
    // vmcnt(6) per phase drains exactly the slice needed 3 phases later.
    stage_a(0, 0, 0); stage_b(0, 0, 0);
    stage_a(0, 1, 0); stage_b(0, 1, 0);
    stage_a(1, 0, 1); stage_b(1, 0, 1);
    waitvm();
    __builtin_amdgcn_sched_barrier(0);
    __builtin_amdgcn_s_barrier();
    for (int it = 0; it < NIT; ++it) {
      const int k1 = 2 * it + 1, k2 = 2 * it + 2, k3 = 2 * it + 3;
      PHASE(0, 0, 0, { stage_a(1, 1, k1); stage_b(1, 1, k1); }, 1)
      PHASE(0, 1, 0, { stage_a(0, 0, k2); stage_b(0, 0, k2); }, 1)
      PHASE(1, 0, 0, { stage_a(0, 1, k2); stage_b(0, 1, k2); }, 1)
      PHASE(1, 1, 0, { stage_a(1, 0, k3); stage_b(1, 0, k3); }, 1)
    }
  }

  const int lq = l >> 4;
  if (M8 == 1) {
    u16* H = (u16*)Cout;
#pragma unroll
    for (int fm = 0; fm < FM; ++fm)
      for (int jj = 0; jj < 4; ++jj) {
        const int m = mtile * 256 + wm * 128 + fm * 16 + lq * 4 + jj;
#pragma unroll
        for (int p = 0; p < 2; ++p) {
          float g = acc[fm][2 * p][jj];
          float u = acc[fm][2 * p + 1][jj];
          // silu(g)*u via exp2 + rcp (bf16-accuracy sufficient; 3x abs-err margin)
          float e = __builtin_amdgcn_exp2f(g * -1.44269504089f);
          float h = g * __builtin_amdgcn_rcpf(1.f + e) * u;
          const int c = ntile * 128 + (wn * 2 + p) * 16 + lr;
          H[(size_t)m * LDHA + c] = f2bf(h);
        }
      }
  } else {
    float* C = (float*)Cout;
#pragma unroll
    for (int fm = 0; fm < FM; ++fm)
#pragma unroll
      for (int n = 0; n < 4; ++n)
        for (int jj = 0; jj < 4; ++jj) {
          const int m = mtile * 128 + wm * 64 + fm * 16 + lq * 4 + jj;
          const int c = ntile * 256 + wn * 64 + n * 16 + lr;
          C[(size_t)m * DM + c] = acc[fm][n][jj];
        }
  }
#undef PHASE
#undef MFMA_Q
}

// ---------------- t_down split-K reduce -> masked SCAL*td into ha ext cols ----------------
__global__ void td_reduce(const float* __restrict__ part,
                          const int* __restrict__ idx,
                          u16* __restrict__ ha) {
  int i = blockIdx.x * blockDim.x + threadIdx.x;
  int m = i >> 7, c = i & 127;
  float s = 0.f;
#pragma unroll
  for (int k = 0; k < 8; ++k) s += part[(size_t)k * NTOK * 128 + i];
  u16 v = ((c >> 4) == idx[m]) ? f2bf(SCAL * s) : (u16)0;
  ha[(size_t)m * LDHA + 8192 + c] = v;
}

extern "C" void kernel_launch(void* const* d_in, const int* in_sizes, int n_in,
                              void* d_out, int out_size, void* d_ws, size_t ws_size,
                              hipStream_t stream) {
  const float* x  = (const float*)d_in[0];
  const float* wg = (const float*)d_in[1];
  const float* wu = (const float*)d_in[2];
  const float* wd = (const float*)d_in[3];
  const float* rw = (const float*)d_in[4];
  const float* rb = (const float*)d_in[5];
  const float* Ag = (const float*)d_in[6];
  const float* Bg = (const float*)d_in[7];
  const float* Au = (const float*)d_in[8];
  const float* Bu = (const float*)d_in[9];
  const float* Ad = (const float*)d_in[10];
  const float* Bd = (const float*)d_in[11];

  float* out      = (float*)d_out;
  float* out_rout = out + (size_t)NTOK * DM;
  float* out_ec   = out_rout + (size_t)NTOK * NEXP;

  char* ws = (char*)d_ws;
  size_t off = 0;
  auto take = [&](size_t b) { void* p = ws + off; off += (b + 255) & ~(size_t)255; return p; };
  u16*   xa   = (u16*)take((size_t)NTOK * LDXA * 2);
  u16*   ha   = (u16*)take((size_t)NTOK * LDHA * 2);
  u16*   wgx  = (u16*)take((size_t)DMLP * LDXA * 2);
  u16*   wux  = (u16*)take((size_t)DMLP * LDXA * 2);
  u16*   wdx  = (u16*)take((size_t)DM * LDHA * 2);
  u16*   Aab  = (u16*)take((size_t)256 * DM * 2);
  u16*   Adb  = (u16*)take((size_t)128 * DMLP * 2);
  float* tdp  = (float*)take((size_t)8 * NTOK * 128 * 4);
  int*   idx  = (int*)take((size_t)NTOK * 4);
  if (off > ws_size) return;

  cvt_kernel<<<64, 256, 0, stream>>>(Ag, Aab, 128 * DM / 4);
  cvt_kernel<<<64, 256, 0, stream>>>(Au, Aab + 128 * DM, 128 * DM / 4);
  cvt_kernel<<<128, 256, 0, stream>>>(Ad, Adb, 128 * DMLP / 4);

  build_wx<<<DMLP, 256, 0, stream>>>(wg, Bg, wgx, DM, LDXA, 0,   DMLP);
  build_wx<<<DMLP, 256, 0, stream>>>(wu, Bu, wux, DM, LDXA, 128, DMLP);
  build_wx<<<DM,   256, 0, stream>>>(wd, Bd, wdx, DMLP, LDHA, 0, DM);

  router_kernel<<<NTOK / 4, 256, 0, stream>>>(x, rw, rb, xa, idx, out_rout, out_ec);

  // t = xa @ [A_gate;A_up]^T -> masked SCAL*t into xa[:, 2048:2304]
  gemm_kernel<0><<<dim3(32, 2), 256, 0, stream>>>(xa, Aab, idx, xa);
  // gate/up fused (lora in K) + silu*mul -> ha[:, 0:8192]   [8-phase 256x256]
  gemm8<256, 36, LDXA, LDXA, 1><<<1024, 512, 0, stream>>>(xa, wgx, wux, ha);
  // t_down partials: ha[:, :8192] @ A_down^T, 8-way K-split
  gemm_kernel<3><<<dim3(32, 8), 256, 0, stream>>>(ha, Adb, idx, tdp);
  td_reduce<<<NTOK * 128 / 256, 256, 0, stream>>>(tdp, idx, ha);
  // down (lora in K) -> f32 out   [4-phase 128x256, 256 blocks]
  gemm8<128, 130, LDHA, LDHA, 2><<<256, 512, 0, stream>>>(ha, wdx, nullptr, out);
}